// Round 6
// baseline (2197.261 us; speedup 1.0000x reference)
//
#include <hip/hip_runtime.h>
#include <hip/hip_bf16.h>
#include <stdint.h>

#define N_NODES 100000
#define IN_CH   128
#define HID     128
#define OUT_CH  64
#define N_EDGES 1600000

#define NB    196      // buckets of 512 nodes
#define NBLK  250      // edge-partition blocks for phases A/B
#define EPB   6400     // edges per block
#define NCW   1563     // 64-node chunks per slice (ceil(100000/64))

typedef __attribute__((ext_vector_type(8))) short  bf16x8;
typedef __attribute__((ext_vector_type(4))) float  f32x4;

// ---------------- helpers ----------------

__device__ __forceinline__ unsigned short f2bf(float f) {   // RNE f32->bf16
    unsigned int u = __float_as_uint(f);
    u = (u + 0x7fffu + ((u >> 16) & 1u)) >> 16;
    return (unsigned short)u;
}
__device__ __forceinline__ float bfl(unsigned int u) { return __uint_as_float(u << 16); }
__device__ __forceinline__ float bfh(unsigned int u) { return __uint_as_float(u & 0xffff0000u); }

// ---------------- CSR build: bucket sort ----------------

__global__ __launch_bounds__(256) void k_phaseA(const int* __restrict__ dst,
                                                int* __restrict__ Cm) {
    __shared__ int hist[NB];
    int blk = blockIdx.x, t = threadIdx.x;
    if (t < NB) hist[t] = 0;
    __syncthreads();
    int base = blk * EPB;
#pragma unroll 5
    for (int k = 0; k < EPB / 256; k++) {
        int d = dst[base + k * 256 + t];
        atomicAdd(&hist[d >> 9], 1);
    }
    __syncthreads();
    if (t < NB) Cm[blk * NB + t] = hist[t];
}

// parallel scan of Cm over blocks: one block per bucket
__global__ __launch_bounds__(256) void k_scanBkt(int* __restrict__ Cm,
                                                 int* __restrict__ bktSum) {
    __shared__ int sdata[256];
    int b = blockIdx.x, t = threadIdx.x;
    int v = (t < NBLK) ? Cm[t * NB + b] : 0;
    sdata[t] = v;
    __syncthreads();
    int val = v;
    for (int off = 1; off < 256; off <<= 1) {
        int tmp = (t >= off) ? sdata[t - off] : 0;
        __syncthreads();
        val += tmp;
        sdata[t] = val;
        __syncthreads();
    }
    if (t < NBLK) Cm[t * NB + b] = val - v;   // exclusive prefix within bucket
    if (t == 255) bktSum[b] = val;
}

__global__ __launch_bounds__(256) void k_scanBase(const int* __restrict__ bktSum,
                                                  int* __restrict__ bktBase) {
    __shared__ int sdata[256];
    int t = threadIdx.x;
    int v = (t < NB) ? bktSum[t] : 0;
    sdata[t] = v;
    __syncthreads();
    int val = v;
    for (int off = 1; off < 256; off <<= 1) {
        int tmp = (t >= off) ? sdata[t - off] : 0;
        __syncthreads();
        val += tmp;
        sdata[t] = val;
        __syncthreads();
    }
    if (t < NB) bktBase[t] = val - v;
    if (t == 0) bktBase[NB] = N_EDGES;
}

__global__ __launch_bounds__(256) void k_phaseB(const int* __restrict__ src,
                                                const int* __restrict__ dst,
                                                const int* __restrict__ Cm,
                                                const int* __restrict__ bktBase,
                                                unsigned int* __restrict__ bucketed) {
    __shared__ int offs[NB];
    int blk = blockIdx.x, t = threadIdx.x;
    if (t < NB) offs[t] = Cm[blk * NB + t] + bktBase[t];
    __syncthreads();
    int base = blk * EPB;
#pragma unroll 5
    for (int k = 0; k < EPB / 256; k++) {
        int e = base + k * 256 + t;
        int d = dst[e];
        int sv = src[e];
        int pos = atomicAdd(&offs[d >> 9], 1);
        bucketed[pos] = ((unsigned int)sv << 9) | (unsigned int)(d & 511);
    }
}

__global__ __launch_bounds__(512) void k_phaseC(const unsigned int* __restrict__ bucketed,
                                                const int* __restrict__ bktBase,
                                                int* __restrict__ rowptr,
                                                float* __restrict__ dinvg,
                                                int* __restrict__ csr_src) {
    __shared__ int cnt[512];
    __shared__ int cur[512];
    __shared__ int sdata[512];
    int b = blockIdx.x, t = threadIdx.x;
    int base = bktBase[b], endR = bktBase[b + 1];
    int nodeBase = b << 9;
    int nNodes = N_NODES - nodeBase;
    if (nNodes > 512) nNodes = 512;

    cnt[t] = 0;
    __syncthreads();
    for (int e = base + t; e < endR; e += 512)
        atomicAdd(&cnt[bucketed[e] & 511], 1);
    __syncthreads();

    int s = cnt[t];
    sdata[t] = s;
    __syncthreads();
    int val = s;
    for (int off = 1; off < 512; off <<= 1) {
        int tmp = (t >= off) ? sdata[t - off] : 0;
        __syncthreads();
        val += tmp;
        sdata[t] = val;
        __syncthreads();
    }
    cur[t] = val - s;
    if (t < nNodes) {
        rowptr[nodeBase + t] = base + val - s;
        dinvg[nodeBase + t] = rsqrtf((float)s + 1.0f);
    }
    if (b == NB - 1 && t == 0) rowptr[N_NODES] = N_EDGES;
    __syncthreads();

    for (int e = base + t; e < endR; e += 512) {
        unsigned int u = bucketed[e];
        int pos = base + atomicAdd(&cur[u & 511], 1);
        csr_src[pos] = (int)(u >> 9);
    }
}

// ---------------- W prep: transpose to bf16 [n][k], fuse mu|ls concat -------
// Also zeroes the sliced-agg work counters (16 ints) each launch/replay.

__global__ __launch_bounds__(256) void k_prepW(const float* __restrict__ W1,
                                               const float* __restrict__ Wmu,
                                               const float* __restrict__ Wls,
                                               unsigned short* __restrict__ Wt1,
                                               unsigned short* __restrict__ WtC,
                                               int* __restrict__ ctr) {
    int idx = blockIdx.x * 256 + threadIdx.x;
    if (blockIdx.x == 0 && threadIdx.x < 16) ctr[threadIdx.x] = 0;
    int n = idx >> 7, k = idx & 127;
    Wt1[idx] = f2bf(W1[k * 128 + n]);
    WtC[idx] = f2bf((n < 64) ? Wmu[k * 64 + n] : Wls[k * 64 + (n - 64)]);
}

// ------ MFMA GEMM1: h0' = dinv*(x@W1), SLICE-MAJOR bf16 [slice][node][16] ---

#define LDA 136

__global__ __launch_bounds__(256) void k_gemm1(const float* __restrict__ X,
                                               const unsigned short* __restrict__ Wt,
                                               const float* __restrict__ dinv,
                                               unsigned short* __restrict__ Y) {
    __shared__ unsigned short sA[128 * LDA];
    int t = threadIdx.x;
    int R0 = blockIdx.x * 128;
    int row = t >> 1, colb = (t & 1) * 64;
    bool valid = (R0 + row) < N_NODES;
    const float* Xr = X + (size_t)(R0 + row) * 128 + colb;
    unsigned short* dp = sA + row * LDA + colb;
#pragma unroll
    for (int j = 0; j < 16; j++) {
        float4 v = valid ? *(const float4*)(Xr + j * 4) : make_float4(0.f, 0.f, 0.f, 0.f);
        ushort4 o;
        o.x = f2bf(v.x); o.y = f2bf(v.y); o.z = f2bf(v.z); o.w = f2bf(v.w);
        *(ushort4*)(dp + j * 4) = o;
    }
    __syncthreads();

    int wv = t >> 6, l = t & 63;
    int quad = l >> 4, lm = l & 15;

    bf16x8 a[2][4];
#pragma unroll
    for (int mt = 0; mt < 2; mt++)
#pragma unroll
        for (int ks = 0; ks < 4; ks++)
            a[mt][ks] = *(const bf16x8*)(sA + (wv * 32 + mt * 16 + lm) * LDA +
                                         ks * 32 + quad * 8);

    f32x4 acc[2][8] = {};
#pragma unroll
    for (int nt = 0; nt < 8; nt++) {
        bf16x8 b[4];
        const unsigned short* Wp = Wt + (nt * 16 + lm) * 128 + quad * 8;
#pragma unroll
        for (int ks = 0; ks < 4; ks++)
            b[ks] = *(const bf16x8*)(Wp + ks * 32);
#pragma unroll
        for (int mt = 0; mt < 2; mt++) {
            f32x4 c = acc[mt][nt];
#pragma unroll
            for (int ks = 0; ks < 4; ks++)
                c = __builtin_amdgcn_mfma_f32_16x16x32_bf16(a[mt][ks], b[ks], c, 0, 0, 0);
            acc[mt][nt] = c;
        }
    }

    int rbase = R0 + wv * 32 + quad * 4;
    float dv[2][4];
#pragma unroll
    for (int mt = 0; mt < 2; mt++)
#pragma unroll
        for (int reg = 0; reg < 4; reg++) {
            int r = rbase + mt * 16 + reg;
            dv[mt][reg] = (r < N_NODES) ? dinv[r] : 0.f;
        }
#pragma unroll
    for (int mt = 0; mt < 2; mt++)
#pragma unroll
        for (int nt = 0; nt < 8; nt++)
#pragma unroll
            for (int reg = 0; reg < 4; reg++) {
                int r = rbase + mt * 16 + reg;
                if (r < N_NODES)
                    Y[((size_t)nt * N_NODES + r) * 16 + lm] =
                        f2bf(acc[mt][nt][reg] * dv[mt][reg]);
            }
}

// ------------- physically XCD-pinned sliced aggregation, v2 (ILP fix) -------
// Routing (proven r4: FETCH 194->78 MB): block reads HW_REG_XCC_ID, claims
// 64-node chunks of ITS OWN XCD's 16-ch slice via per-slice atomic queues;
// 8-slice steal sweep guarantees completion for any dispatch (G16).
// v2 execution shape (fixes r4's 451us latency serialization):
//  - wave-level claims (no block barriers); plain-load guard before atomic
//  - chunk rowptr/dinv preloaded into regs, per-node via shfl
//  - csr: 64 edges per wave-load into regs; per-batch src ids via shfl(E,..)
//    -> csr off the per-edge critical path; next node's E prefetched
//  - lane = (slot sj=l>>2, half h=l&3), uint2 gather: 16 rows/instr,
//    4 batches in flight -> up to 64 rows outstanding per node
// Inputs pre-scaled (h' = d*h): agg_i = d_i*(h'_i + sum_j h'_j).

template<int LAYER>
__global__ __launch_bounds__(256, 8) void k_aggx(const unsigned short* __restrict__ Hin,
                                                 const int* __restrict__ rowptr,
                                                 const int* __restrict__ csr_src,
                                                 const float* __restrict__ dinv,
                                                 const float* __restrict__ bias,
                                                 unsigned short* __restrict__ Hout,
                                                 int* __restrict__ ctr) {
    int t = threadIdx.x;
    int l = t & 63;
    int sj = l >> 2;           // edge slot 0..15
    int h  = l & 3;            // row half: 8 B at byte offset h*8
    unsigned int xcd;
    asm volatile("s_getreg_b32 %0, hwreg(HW_REG_XCC_ID)" : "=s"(xcd));
    xcd &= 7u;
    int* bc = ctr + (LAYER == 1 ? 0 : 8);

    for (int ss = 0; ss < 8; ss++) {
        int slice = (int)((xcd + (unsigned)ss) & 7u);
        const unsigned short* Hs = Hin + (size_t)slice * ((size_t)N_NODES * 16);
        int* cp = bc + slice;
        for (;;) {
            if (__builtin_nontemporal_load(cp) >= NCW) break;   // cheap guard
            int c0 = 0;
            if (l == 0) c0 = atomicAdd(cp, 1);
            int c = __shfl(c0, 0);
            if (c >= NCW) break;
            int nb = c * 64;

            // chunk preload: rowptr[nb..nb+63] and dinv -> regs
            int ridx = nb + l;  if (ridx > N_NODES) ridx = N_NODES;
            int R = rowptr[ridx];
            int rl = nb + 64;   if (rl > N_NODES) rl = N_NODES;
            int Rlast = rowptr[rl];
            int didx = nb + l;  if (didx >= N_NODES) didx = N_NODES - 1;
            float Dv = dinv[didx];

            // prefetch csr for node 0
            int E, E_next;
            {
                int b0 = __shfl(R, 0);
                int e0 = __shfl(R, 1);
                int q = b0 + l; if (q >= e0) q = e0 - 1; if (q < 0) q = 0;
                E_next = csr_src[q];
            }

            for (int n0 = 0; n0 < 64; n0++) {
                int node = nb + n0;
                int beg = __shfl(R, n0);
                int end = (n0 < 63) ? __shfl(R, n0 + 1) : Rlast;
                int deg = end - beg;
                E = E_next;
                if (n0 < 63) {           // prefetch next node's csr (beg_{n+1}=end)
                    int endN = (n0 < 62) ? __shfl(R, n0 + 2) : Rlast;
                    int q = end + l; if (q >= endN) q = endN - 1; if (q < 0) q = 0;
                    E_next = csr_src[q];
                }

                int nl = node < N_NODES ? node : 0;
                uint2 sv = *(const uint2*)(Hs + (size_t)nl * 16 + h * 4);
                float a0 = (sj == 0) ? bfl(sv.x) : 0.f;
                float a1 = (sj == 0) ? bfh(sv.x) : 0.f;
                float a2 = (sj == 0) ? bfl(sv.y) : 0.f;
                float a3 = (sj == 0) ? bfh(sv.y) : 0.f;

                for (int base = 0; base < deg; base += 64) {
                    if (base > 0) {      // rare tail: reload csr window
                        int q = beg + base + l; if (q >= end) q = end - 1;
                        E = csr_src[q];
                    }
#pragma unroll
                    for (int p = 0; p < 64; p += 16) {
                        if (base + p >= deg) break;
                        int s = __shfl(E, p + sj);
                        uint2 v = make_uint2(0u, 0u);
                        if (base + p + sj < deg)
                            v = *(const uint2*)(Hs + (size_t)s * 16 + h * 4);
                        a0 += bfl(v.x); a1 += bfh(v.x);
                        a2 += bfl(v.y); a3 += bfh(v.y);
                    }
                }

#pragma unroll
                for (int off = 4; off < 64; off <<= 1) {
                    a0 += __shfl_xor(a0, off); a1 += __shfl_xor(a1, off);
                    a2 += __shfl_xor(a2, off); a3 += __shfl_xor(a3, off);
                }
                float di = __shfl(Dv, n0);
                if (sj == 0 && node < N_NODES) {
                    if (LAYER == 1) {
                        float4 bv = *(const float4*)(bias + slice * 16 + h * 4);
                        a0 = a0 * di + bv.x;
                        a1 = a1 * di + bv.y;
                        a2 = a2 * di + bv.z;
                        a3 = a3 * di + bv.w;
                        a0 = a0 > 0.f ? a0 : 0.f;
                        a1 = a1 > 0.f ? a1 : 0.f;
                        a2 = a2 > 0.f ? a2 : 0.f;
                        a3 = a3 > 0.f ? a3 : 0.f;
                        a0 *= di; a1 *= di; a2 *= di; a3 *= di;  // pre-scale for L2 gather
                        uint2 o;
                        o.x = ((unsigned int)f2bf(a1) << 16) | (unsigned int)f2bf(a0);
                        o.y = ((unsigned int)f2bf(a3) << 16) | (unsigned int)f2bf(a2);
                        *(uint2*)(Hout + ((size_t)slice * N_NODES + node) * 16 + h * 4) = o;
                    } else {
                        a0 *= di; a1 *= di; a2 *= di; a3 *= di;
                        unsigned int ox = ((unsigned int)f2bf(a1) << 16) | (unsigned int)f2bf(a0);
                        unsigned int oy = ((unsigned int)f2bf(a3) << 16) | (unsigned int)f2bf(a2);
                        unsigned int* op =
                            (unsigned int*)(Hout + (size_t)node * 128 + slice * 16 + h * 4);
                        __builtin_nontemporal_store(ox, op);
                        __builtin_nontemporal_store(oy, op + 1);
                    }
                }
            }
        }
    }
}

// ---------------- MFMA GEMM2: g[bf16 node-major] @ WtC + bias -> out --------

__global__ __launch_bounds__(256) void k_gemm2(const unsigned short* __restrict__ G,
                                               const unsigned short* __restrict__ Wt,
                                               const float* __restrict__ bmu,
                                               const float* __restrict__ bls,
                                               float* __restrict__ out) {
    __shared__ unsigned short sA[128 * LDA];
    int t = threadIdx.x;
    int R0 = blockIdx.x * 128;
    int row = t >> 1, colb = (t & 1) * 64;
    bool valid = (R0 + row) < N_NODES;
    const unsigned short* Gr = G + (size_t)(R0 + row) * 128 + colb;
    unsigned short* dp = sA + row * LDA + colb;
#pragma unroll
    for (int j = 0; j < 8; j++) {
        bf16x8 v = {0, 0, 0, 0, 0, 0, 0, 0};
        if (valid) v = *(const bf16x8*)(Gr + j * 8);
        *(bf16x8*)(dp + j * 8) = v;
    }
    __syncthreads();

    int wv = t >> 6, l = t & 63;
    int quad = l >> 4, lm = l & 15;

    bf16x8 a[2][4];
#pragma unroll
    for (int mt = 0; mt < 2; mt++)
#pragma unroll
        for (int ks = 0; ks < 4; ks++)
            a[mt][ks] = *(const bf16x8*)(sA + (wv * 32 + mt * 16 + lm) * LDA +
                                         ks * 32 + quad * 8);

    f32x4 acc[2][8] = {};
#pragma unroll
    for (int nt = 0; nt < 8; nt++) {
        bf16x8 b[4];
        const unsigned short* Wp = Wt + (nt * 16 + lm) * 128 + quad * 8;
#pragma unroll
        for (int ks = 0; ks < 4; ks++)
            b[ks] = *(const bf16x8*)(Wp + ks * 32);
#pragma unroll
        for (int mt = 0; mt < 2; mt++) {
            f32x4 c = acc[mt][nt];
#pragma unroll
            for (int ks = 0; ks < 4; ks++)
                c = __builtin_amdgcn_mfma_f32_16x16x32_bf16(a[mt][ks], b[ks], c, 0, 0, 0);
            acc[mt][nt] = c;
        }
    }

    int rbase = R0 + wv * 32 + quad * 4;
#pragma unroll
    for (int mt = 0; mt < 2; mt++)
#pragma unroll
        for (int nt = 0; nt < 8; nt++) {
            int col = nt * 16 + lm;
#pragma unroll
            for (int reg = 0; reg < 4; reg++) {
                int r = rbase + mt * 16 + reg;
                if (r < N_NODES) {
                    float v = acc[mt][nt][reg];
                    if (col < 64)
                        out[(size_t)r * 64 + col] = v + bmu[col];
                    else
                        out[(size_t)N_NODES * 64 + (size_t)r * 64 + (col - 64)] = v + bls[col - 64];
                }
            }
        }
}

// ---------------- launch ----------------

extern "C" void kernel_launch(void* const* d_in, const int* in_sizes, int n_in,
                              void* d_out, int out_size, void* d_ws, size_t ws_size,
                              hipStream_t stream) {
    const float* x    = (const float*)d_in[0];
    const int*   ei   = (const int*)d_in[1];
    const float* W1   = (const float*)d_in[2];
    const float* b1   = (const float*)d_in[3];
    const float* Wmu  = (const float*)d_in[4];
    const float* bmu  = (const float*)d_in[5];
    const float* Wls  = (const float*)d_in[6];
    const float* bls  = (const float*)d_in[7];
    const int* src = ei;
    const int* dst = ei + N_EDGES;

    char* p = (char*)d_ws;
    unsigned short* bufA = (unsigned short*)p; p += (size_t)N_NODES * 128 * 2; // h0' sliced; later g node-major
    unsigned short* bufH = (unsigned short*)p; p += (size_t)N_NODES * 128 * 2; // hb' sliced
    unsigned short* Wt1  = (unsigned short*)p; p += 128 * 128 * 2;
    unsigned short* WtC  = (unsigned short*)p; p += 128 * 128 * 2;
    int*   Cm      = (int*)p;   p += (size_t)NBLK * NB * 4;
    int*   bktSum  = (int*)p;   p += 256 * 4;
    int*   bktBase = (int*)p;   p += 256 * 4;
    int*   rowptr  = (int*)p;   p += 400016;
    float* dinv    = (float*)p; p += 400000;
    unsigned int* bucketed = (unsigned int*)p; p += (size_t)N_EDGES * 4;
    int*   csr_src = (int*)p;   p += (size_t)N_EDGES * 4;
    int*   ctr     = (int*)p;   p += 64 * 4;

    // CSR build
    k_phaseA<<<NBLK, 256, 0, stream>>>(dst, Cm);
    k_scanBkt<<<NB, 256, 0, stream>>>(Cm, bktSum);
    k_scanBase<<<1, 256, 0, stream>>>(bktSum, bktBase);
    k_phaseB<<<NBLK, 256, 0, stream>>>(src, dst, Cm, bktBase, bucketed);
    k_phaseC<<<NB, 512, 0, stream>>>(bucketed, bktBase, rowptr, dinv, csr_src);

    k_prepW<<<64, 256, 0, stream>>>(W1, Wmu, Wls, Wt1, WtC, ctr);

    int gblk = (N_NODES + 127) / 128;   // 782

    // layer 1: h0' = dinv*(x@W1) (sliced) ; hb' = dinv*relu(dinv*agg+b1) (sliced)
    k_gemm1<<<gblk, 256, 0, stream>>>(x, Wt1, dinv, bufA);
    k_aggx<1><<<2048, 256, 0, stream>>>(bufA, rowptr, csr_src, dinv, b1, bufH, ctr);

    // layer 2: g = dinv*(self+sum hb') (node-major) ; out = g @ [Wmu|Wls] + bias
    k_aggx<2><<<2048, 256, 0, stream>>>(bufH, rowptr, csr_src, dinv, b1, bufA, ctr);
    k_gemm2<<<gblk, 256, 0, stream>>>(bufA, WtC, bmu, bls, (float*)d_out);
}

// Round 7
// 352.204 us; speedup vs baseline: 6.2386x; 6.2386x over previous
//
#include <hip/hip_runtime.h>
#include <hip/hip_bf16.h>
#include <stdint.h>

#define N_NODES 100000
#define IN_CH   128
#define HID     128
#define OUT_CH  64
#define N_EDGES 1600000

#define NB    196      // buckets of 512 nodes
#define NBLK  250      // edge-partition blocks for phases A/B
#define EPB   6400     // edges per block

typedef __attribute__((ext_vector_type(8))) short  bf16x8;
typedef __attribute__((ext_vector_type(4))) float  f32x4;

// ---------------- helpers ----------------

__device__ __forceinline__ unsigned short f2bf(float f) {   // RNE f32->bf16
    unsigned int u = __float_as_uint(f);
    u = (u + 0x7fffu + ((u >> 16) & 1u)) >> 16;
    return (unsigned short)u;
}
__device__ __forceinline__ float bfl(unsigned int u) { return __uint_as_float(u << 16); }
__device__ __forceinline__ float bfh(unsigned int u) { return __uint_as_float(u & 0xffff0000u); }

// ---------------- CSR build: bucket sort ----------------

__global__ __launch_bounds__(256) void k_phaseA(const int* __restrict__ dst,
                                                int* __restrict__ Cm) {
    __shared__ int hist[NB];
    int blk = blockIdx.x, t = threadIdx.x;
    if (t < NB) hist[t] = 0;
    __syncthreads();
    int base = blk * EPB;
#pragma unroll 5
    for (int k = 0; k < EPB / 256; k++) {
        int d = dst[base + k * 256 + t];
        atomicAdd(&hist[d >> 9], 1);
    }
    __syncthreads();
    if (t < NB) Cm[blk * NB + t] = hist[t];
}

// parallel scan of Cm over blocks: one block per bucket
__global__ __launch_bounds__(256) void k_scanBkt(int* __restrict__ Cm,
                                                 int* __restrict__ bktSum) {
    __shared__ int sdata[256];
    int b = blockIdx.x, t = threadIdx.x;
    int v = (t < NBLK) ? Cm[t * NB + b] : 0;
    sdata[t] = v;
    __syncthreads();
    int val = v;
    for (int off = 1; off < 256; off <<= 1) {
        int tmp = (t >= off) ? sdata[t - off] : 0;
        __syncthreads();
        val += tmp;
        sdata[t] = val;
        __syncthreads();
    }
    if (t < NBLK) Cm[t * NB + b] = val - v;   // exclusive prefix within bucket
    if (t == 255) bktSum[b] = val;
}

__global__ __launch_bounds__(256) void k_scanBase(const int* __restrict__ bktSum,
                                                  int* __restrict__ bktBase) {
    __shared__ int sdata[256];
    int t = threadIdx.x;
    int v = (t < NB) ? bktSum[t] : 0;
    sdata[t] = v;
    __syncthreads();
    int val = v;
    for (int off = 1; off < 256; off <<= 1) {
        int tmp = (t >= off) ? sdata[t - off] : 0;
        __syncthreads();
        val += tmp;
        sdata[t] = val;
        __syncthreads();
    }
    if (t < NB) bktBase[t] = val - v;
    if (t == 0) bktBase[NB] = N_EDGES;
}

__global__ __launch_bounds__(256) void k_phaseB(const int* __restrict__ src,
                                                const int* __restrict__ dst,
                                                const int* __restrict__ Cm,
                                                const int* __restrict__ bktBase,
                                                unsigned int* __restrict__ bucketed) {
    __shared__ int offs[NB];
    int blk = blockIdx.x, t = threadIdx.x;
    if (t < NB) offs[t] = Cm[blk * NB + t] + bktBase[t];
    __syncthreads();
    int base = blk * EPB;
#pragma unroll 5
    for (int k = 0; k < EPB / 256; k++) {
        int e = base + k * 256 + t;
        int d = dst[e];
        int sv = src[e];
        int pos = atomicAdd(&offs[d >> 9], 1);
        bucketed[pos] = ((unsigned int)sv << 9) | (unsigned int)(d & 511);
    }
}

__global__ __launch_bounds__(512) void k_phaseC(const unsigned int* __restrict__ bucketed,
                                                const int* __restrict__ bktBase,
                                                int* __restrict__ rowptr,
                                                float* __restrict__ dinvg,
                                                int* __restrict__ csr_src) {
    __shared__ int cnt[512];
    __shared__ int cur[512];
    __shared__ int sdata[512];
    int b = blockIdx.x, t = threadIdx.x;
    int base = bktBase[b], endR = bktBase[b + 1];
    int nodeBase = b << 9;
    int nNodes = N_NODES - nodeBase;
    if (nNodes > 512) nNodes = 512;

    cnt[t] = 0;
    __syncthreads();
    for (int e = base + t; e < endR; e += 512)
        atomicAdd(&cnt[bucketed[e] & 511], 1);
    __syncthreads();

    int s = cnt[t];
    sdata[t] = s;
    __syncthreads();
    int val = s;
    for (int off = 1; off < 512; off <<= 1) {
        int tmp = (t >= off) ? sdata[t - off] : 0;
        __syncthreads();
        val += tmp;
        sdata[t] = val;
        __syncthreads();
    }
    cur[t] = val - s;
    if (t < nNodes) {
        rowptr[nodeBase + t] = base + val - s;
        dinvg[nodeBase + t] = rsqrtf((float)s + 1.0f);
    }
    if (b == NB - 1 && t == 0) rowptr[N_NODES] = N_EDGES;
    __syncthreads();

    for (int e = base + t; e < endR; e += 512) {
        unsigned int u = bucketed[e];
        int pos = base + atomicAdd(&cur[u & 511], 1);
        csr_src[pos] = (int)(u >> 9);
    }
}

// ---------------- W prep: transpose to bf16 [n][k], fuse mu|ls concat -------

__global__ __launch_bounds__(256) void k_prepW(const float* __restrict__ W1,
                                               const float* __restrict__ Wmu,
                                               const float* __restrict__ Wls,
                                               unsigned short* __restrict__ Wt1,
                                               unsigned short* __restrict__ WtC) {
    int idx = blockIdx.x * 256 + threadIdx.x;
    int n = idx >> 7, k = idx & 127;
    Wt1[idx] = f2bf(W1[k * 128 + n]);
    WtC[idx] = f2bf((n < 64) ? Wmu[k * 64 + n] : Wls[k * 64 + (n - 64)]);
}

// ------ MFMA GEMM1: h0' = dinv * (x @ W1), node-major bf16 [node][128] ------

#define LDA 136

__global__ __launch_bounds__(256) void k_gemm1(const float* __restrict__ X,
                                               const unsigned short* __restrict__ Wt,
                                               const float* __restrict__ dinv,
                                               unsigned short* __restrict__ Y) {
    __shared__ unsigned short sA[128 * LDA];
    int t = threadIdx.x;
    int R0 = blockIdx.x * 128;
    int row = t >> 1, colb = (t & 1) * 64;
    bool valid = (R0 + row) < N_NODES;
    const float* Xr = X + (size_t)(R0 + row) * 128 + colb;
    unsigned short* dp = sA + row * LDA + colb;
#pragma unroll
    for (int j = 0; j < 16; j++) {
        float4 v = valid ? *(const float4*)(Xr + j * 4) : make_float4(0.f, 0.f, 0.f, 0.f);
        ushort4 o;
        o.x = f2bf(v.x); o.y = f2bf(v.y); o.z = f2bf(v.z); o.w = f2bf(v.w);
        *(ushort4*)(dp + j * 4) = o;
    }
    __syncthreads();

    int wv = t >> 6, l = t & 63;
    int quad = l >> 4, lm = l & 15;

    bf16x8 a[2][4];
#pragma unroll
    for (int mt = 0; mt < 2; mt++)
#pragma unroll
        for (int ks = 0; ks < 4; ks++)
            a[mt][ks] = *(const bf16x8*)(sA + (wv * 32 + mt * 16 + lm) * LDA +
                                         ks * 32 + quad * 8);

    f32x4 acc[2][8] = {};
#pragma unroll
    for (int nt = 0; nt < 8; nt++) {
        bf16x8 b[4];
        const unsigned short* Wp = Wt + (nt * 16 + lm) * 128 + quad * 8;
#pragma unroll
        for (int ks = 0; ks < 4; ks++)
            b[ks] = *(const bf16x8*)(Wp + ks * 32);
#pragma unroll
        for (int mt = 0; mt < 2; mt++) {
            f32x4 c = acc[mt][nt];
#pragma unroll
            for (int ks = 0; ks < 4; ks++)
                c = __builtin_amdgcn_mfma_f32_16x16x32_bf16(a[mt][ks], b[ks], c, 0, 0, 0);
            acc[mt][nt] = c;
        }
    }

    int rbase = R0 + wv * 32 + quad * 4;
    float dv[2][4];
#pragma unroll
    for (int mt = 0; mt < 2; mt++)
#pragma unroll
        for (int reg = 0; reg < 4; reg++) {
            int r = rbase + mt * 16 + reg;
            dv[mt][reg] = (r < N_NODES) ? dinv[r] : 0.f;
        }
#pragma unroll
    for (int mt = 0; mt < 2; mt++)
#pragma unroll
        for (int nt = 0; nt < 8; nt++)
#pragma unroll
            for (int reg = 0; reg < 4; reg++) {
                int r = rbase + mt * 16 + reg;
                if (r < N_NODES)
                    Y[(size_t)r * 128 + nt * 16 + lm] = f2bf(acc[mt][nt][reg] * dv[mt][reg]);
            }
}

// -------- agg1: hb' = dinv * relu(dinv * (self + sum h0') + b1) -------------
// Reshaped to agg2g's proven structure: 16 nodes/block, 4 waves, 4 serial
// nodes per wave (j4 loop overlaps successive nodes' 32-deep gather batches).
// Inputs pre-scaled (h0' = d*h0): per-edge weight is 1, no dinv gather.

__global__ __launch_bounds__(256) void k_agg1(const unsigned short* __restrict__ h0,
                                              const int* __restrict__ rowptr,
                                              const int* __restrict__ csr_src,
                                              const float* __restrict__ dinv,
                                              const float* __restrict__ b1,
                                              unsigned short* __restrict__ hb) {
    int t = threadIdx.x;
    int wv = t >> 6, lane = t & 63;
    int nodeBase = blockIdx.x * 16;
    int c2 = lane * 2;

#pragma unroll 1
    for (int j4 = 0; j4 < 4; j4++) {
        int i = __builtin_amdgcn_readfirstlane(nodeBase + wv * 4 + j4);
        float di = dinv[i];
        unsigned int sv = *(const unsigned int*)(h0 + (size_t)i * 128 + c2);
        float ax = bfl(sv), ay = bfh(sv);        // self term, weight 1
        int beg = rowptr[i], end = rowptr[i + 1];
        for (int p = beg; p < end; p += 32) {
            int s[32]; unsigned int r[32];
#pragma unroll
            for (int j = 0; j < 32; j++) {
                int q = p + j;
                s[j] = __builtin_nontemporal_load(csr_src + (q < end ? q : end - 1));
            }
#pragma unroll
            for (int j = 0; j < 32; j++)
                r[j] = *(const unsigned int*)(h0 + (size_t)s[j] * 128 + c2);
#pragma unroll
            for (int j = 0; j < 32; j++) {
                unsigned int v = (p + j < end) ? r[j] : 0u;
                ax += bfl(v);
                ay += bfh(v);
            }
        }
        ax = ax * di + b1[c2];
        ay = ay * di + b1[c2 + 1];
        ax = ax > 0.f ? ax : 0.f;
        ay = ay > 0.f ? ay : 0.f;
        ax *= di;                                // pre-scale for layer-2 gather
        ay *= di;
        unsigned int pk = ((unsigned int)f2bf(ay) << 16) | (unsigned int)f2bf(ax);
        *(unsigned int*)(hb + (size_t)i * 128 + c2) = pk;
    }
}

// ------- fused layer 2: g = dinv*(self + sum hb'); out = g @ WtC + bias -----
// Block = 256 thr / 4 waves / 16 nodes. Same batch-32 pre-scaled gather loop.

#define LDG 136

__global__ __launch_bounds__(256) void k_agg2g(const unsigned short* __restrict__ hb,
                                               const int* __restrict__ rowptr,
                                               const int* __restrict__ csr_src,
                                               const float* __restrict__ dinv,
                                               const unsigned short* __restrict__ WtC,
                                               const float* __restrict__ bmu,
                                               const float* __restrict__ bls,
                                               float* __restrict__ out) {
    __shared__ unsigned short g[16 * LDG];
    int t = threadIdx.x;
    int wv = t >> 6, lane = t & 63;
    int nodeBase = blockIdx.x * 16;
    int c2 = lane * 2;

#pragma unroll 1
    for (int j4 = 0; j4 < 4; j4++) {
        int i = __builtin_amdgcn_readfirstlane(nodeBase + wv * 4 + j4);
        float di = dinv[i];
        unsigned int sv = *(const unsigned int*)(hb + (size_t)i * 128 + c2);
        float ax = bfl(sv), ay = bfh(sv);
        int beg = rowptr[i], end = rowptr[i + 1];
        for (int p = beg; p < end; p += 32) {
            int s[32]; unsigned int r[32];
#pragma unroll
            for (int j = 0; j < 32; j++) {
                int q = p + j;
                s[j] = __builtin_nontemporal_load(csr_src + (q < end ? q : end - 1));
            }
#pragma unroll
            for (int j = 0; j < 32; j++)
                r[j] = *(const unsigned int*)(hb + (size_t)s[j] * 128 + c2);
#pragma unroll
            for (int j = 0; j < 32; j++) {
                unsigned int v = (p + j < end) ? r[j] : 0u;
                ax += bfl(v);
                ay += bfh(v);
            }
        }
        ax *= di;
        ay *= di;
        unsigned int pk = ((unsigned int)f2bf(ay) << 16) | (unsigned int)f2bf(ax);
        *(unsigned int*)(g + (wv * 4 + j4) * LDG + c2) = pk;
    }
    __syncthreads();

    // MFMA: wave wv computes output cols [wv*32, wv*32+32)
    int quad = lane >> 4, lm = lane & 15;
    bf16x8 a[4];
#pragma unroll
    for (int ks = 0; ks < 4; ks++)
        a[ks] = *(const bf16x8*)(g + lm * LDG + ks * 32 + quad * 8);

#pragma unroll
    for (int nt2 = 0; nt2 < 2; nt2++) {
        int nt = wv * 2 + nt2;
        f32x4 acc = {};
        const unsigned short* Wp = WtC + (nt * 16 + lm) * 128 + quad * 8;
#pragma unroll
        for (int ks = 0; ks < 4; ks++) {
            bf16x8 b = *(const bf16x8*)(Wp + ks * 32);
            acc = __builtin_amdgcn_mfma_f32_16x16x32_bf16(a[ks], b, acc, 0, 0, 0);
        }
        int col = nt * 16 + lm;
#pragma unroll
        for (int reg = 0; reg < 4; reg++) {
            int row = nodeBase + quad * 4 + reg;
            float v = acc[reg];
            if (col < 64)
                out[(size_t)row * 64 + col] = v + bmu[col];
            else
                out[(size_t)N_NODES * 64 + (size_t)row * 64 + (col - 64)] = v + bls[col - 64];
        }
    }
}

// ---------------- launch ----------------

extern "C" void kernel_launch(void* const* d_in, const int* in_sizes, int n_in,
                              void* d_out, int out_size, void* d_ws, size_t ws_size,
                              hipStream_t stream) {
    const float* x    = (const float*)d_in[0];
    const int*   ei   = (const int*)d_in[1];
    const float* W1   = (const float*)d_in[2];
    const float* b1   = (const float*)d_in[3];
    const float* Wmu  = (const float*)d_in[4];
    const float* bmu  = (const float*)d_in[5];
    const float* Wls  = (const float*)d_in[6];
    const float* bls  = (const float*)d_in[7];
    const int* src = ei;
    const int* dst = ei + N_EDGES;

    char* p = (char*)d_ws;
    unsigned short* bufA = (unsigned short*)p; p += (size_t)N_NODES * 128 * 2; // h0' (bf16, pre-scaled)
    unsigned short* bufH = (unsigned short*)p; p += (size_t)N_NODES * 128 * 2; // hb' (bf16, pre-scaled)
    unsigned short* Wt1  = (unsigned short*)p; p += 128 * 128 * 2;
    unsigned short* WtC  = (unsigned short*)p; p += 128 * 128 * 2;
    int*   Cm      = (int*)p;   p += (size_t)NBLK * NB * 4;
    int*   bktSum  = (int*)p;   p += 256 * 4;
    int*   bktBase = (int*)p;   p += 256 * 4;
    int*   rowptr  = (int*)p;   p += 400016;
    float* dinv    = (float*)p; p += 400000;
    unsigned int* bucketed = (unsigned int*)p; p += (size_t)N_EDGES * 4;
    int*   csr_src = (int*)p;   p += (size_t)N_EDGES * 4;

    // CSR build
    k_phaseA<<<NBLK, 256, 0, stream>>>(dst, Cm);
    k_scanBkt<<<NB, 256, 0, stream>>>(Cm, bktSum);
    k_scanBase<<<1, 256, 0, stream>>>(bktSum, bktBase);
    k_phaseB<<<NBLK, 256, 0, stream>>>(src, dst, Cm, bktBase, bucketed);
    k_phaseC<<<NB, 512, 0, stream>>>(bucketed, bktBase, rowptr, dinv, csr_src);

    k_prepW<<<64, 256, 0, stream>>>(W1, Wmu, Wls, Wt1, WtC);

    int gblk = (N_NODES + 127) / 128;   // 782

    // layer 1: h0' = dinv * (x @ W1) (MFMA) ; hb' = dinv*relu(dinv*agg + b1)
    k_gemm1<<<gblk, 256, 0, stream>>>(x, Wt1, dinv, bufA);
    k_agg1<<<N_NODES / 16, 256, 0, stream>>>(bufA, rowptr, csr_src, dinv, b1, bufH);

    // layer 2 (reordered): out = (dinv*(self+sum hb')) @ [Wmu|Wls] + bias, fused
    k_agg2g<<<N_NODES / 16, 256, 0, stream>>>(bufH, rowptr, csr_src, dinv,
                                              WtC, bmu, bls, (float*)d_out);
}

// Round 8
// 347.922 us; speedup vs baseline: 6.3154x; 1.0123x over previous
//
#include <hip/hip_runtime.h>
#include <hip/hip_bf16.h>
#include <stdint.h>

#define N_NODES 100000
#define IN_CH   128
#define HID     128
#define OUT_CH  64
#define N_EDGES 1600000

#define NB    196      // buckets of 512 nodes
#define NBLK  250      // edge-partition blocks for scatter
#define EPB   6400     // edges per block
#define CAP   10240    // padded bucket capacity (mean 8192, sigma~90)

typedef __attribute__((ext_vector_type(8))) short  bf16x8;
typedef __attribute__((ext_vector_type(4))) float  f32x4;

// ---------------- helpers ----------------

__device__ __forceinline__ unsigned short f2bf(float f) {   // RNE f32->bf16
    unsigned int u = __float_as_uint(f);
    u = (u + 0x7fffu + ((u >> 16) & 1u)) >> 16;
    return (unsigned short)u;
}
__device__ __forceinline__ float bfl(unsigned int u) { return __uint_as_float(u << 16); }
__device__ __forceinline__ float bfh(unsigned int u) { return __uint_as_float(u & 0xffff0000u); }

// ------------- CSR build, single-pass scatter (fused A+scan+B) --------------
// Per-block LDS histogram of its 6400 edges; block reserves per-bucket space
// via one global atomicAdd per bucket; scatters into capacity-padded buckets.
// Within-bucket order is non-deterministic (harmless: fp32 accum, reorder
// noise ~1e-7 << bf16 quantization).

__global__ __launch_bounds__(256) void k_scatter1(const int* __restrict__ src,
                                                  const int* __restrict__ dst,
                                                  int* __restrict__ bucketCnt,
                                                  unsigned int* __restrict__ bucketed) {
    __shared__ int hist[NB];
    int blk = blockIdx.x, t = threadIdx.x;
    if (t < NB) hist[t] = 0;
    __syncthreads();
    int base = blk * EPB;
#pragma unroll 5
    for (int k = 0; k < EPB / 256; k++) {
        int d = dst[base + k * 256 + t];
        atomicAdd(&hist[d >> 9], 1);
    }
    __syncthreads();
    if (t < NB) hist[t] = atomicAdd(&bucketCnt[t], hist[t]);   // reserve
    __syncthreads();
#pragma unroll 5
    for (int k = 0; k < EPB / 256; k++) {
        int e = base + k * 256 + t;
        int d = dst[e];
        int sv = src[e];
        int pos = atomicAdd(&hist[d >> 9], 1);
        bucketed[(size_t)(d >> 9) * CAP + pos] =
            ((unsigned int)sv << 9) | (unsigned int)(d & 511);
    }
}

// ------------- phaseC': per-bucket node sort -> CSR + dinv ------------------
// Each block scans the 196-entry bucketCnt in-LDS to get its global CSR base
// (replaces the old bktBase kernel), then counts/sorts nodes within bucket.

__global__ __launch_bounds__(512) void k_phaseC(const unsigned int* __restrict__ bucketed,
                                                const int* __restrict__ bucketCnt,
                                                int* __restrict__ rowptr,
                                                float* __restrict__ dinvg,
                                                int* __restrict__ csr_src) {
    __shared__ int cnt[512];
    __shared__ int cur[512];
    __shared__ int sdata[512];
    __shared__ int s_base, s_cnt;
    int b = blockIdx.x, t = threadIdx.x;

    // in-block exclusive scan of bucket counts -> global base of bucket b
    int bv = (t < NB) ? bucketCnt[t] : 0;
    sdata[t] = bv;
    __syncthreads();
    int bval = bv;
    for (int off = 1; off < 512; off <<= 1) {
        int tmp = (t >= off) ? sdata[t - off] : 0;
        __syncthreads();
        bval += tmp;
        sdata[t] = bval;
        __syncthreads();
    }
    if (t == b) { s_base = bval - bv; s_cnt = bv; }
    __syncthreads();
    int base = s_base;
    int nEdge = s_cnt;

    const unsigned int* bk = bucketed + (size_t)b * CAP;
    int nodeBase = b << 9;
    int nNodes = N_NODES - nodeBase;
    if (nNodes > 512) nNodes = 512;

    cnt[t] = 0;
    __syncthreads();
    for (int e = t; e < nEdge; e += 512)
        atomicAdd(&cnt[bk[e] & 511], 1);
    __syncthreads();

    int s = cnt[t];
    sdata[t] = s;
    __syncthreads();
    int val = s;
    for (int off = 1; off < 512; off <<= 1) {
        int tmp = (t >= off) ? sdata[t - off] : 0;
        __syncthreads();
        val += tmp;
        sdata[t] = val;
        __syncthreads();
    }
    cur[t] = val - s;
    if (t < nNodes) {
        rowptr[nodeBase + t] = base + val - s;
        dinvg[nodeBase + t] = rsqrtf((float)s + 1.0f);
    }
    if (b == NB - 1 && t == 0) rowptr[N_NODES] = N_EDGES;
    __syncthreads();

    for (int e = t; e < nEdge; e += 512) {
        unsigned int u = bk[e];
        int pos = base + atomicAdd(&cur[u & 511], 1);
        csr_src[pos] = (int)(u >> 9);
    }
}

// ---------------- W prep: transpose to bf16 [n][k], fuse mu|ls concat -------

__global__ __launch_bounds__(256) void k_prepW(const float* __restrict__ W1,
                                               const float* __restrict__ Wmu,
                                               const float* __restrict__ Wls,
                                               unsigned short* __restrict__ Wt1,
                                               unsigned short* __restrict__ WtC) {
    int idx = blockIdx.x * 256 + threadIdx.x;
    int n = idx >> 7, k = idx & 127;
    Wt1[idx] = f2bf(W1[k * 128 + n]);
    WtC[idx] = f2bf((n < 64) ? Wmu[k * 64 + n] : Wls[k * 64 + (n - 64)]);
}

// ------ MFMA GEMM1: h0' = dinv * (x @ W1), node-major bf16 [node][128] ------

#define LDA 136

__global__ __launch_bounds__(256) void k_gemm1(const float* __restrict__ X,
                                               const unsigned short* __restrict__ Wt,
                                               const float* __restrict__ dinv,
                                               unsigned short* __restrict__ Y) {
    __shared__ unsigned short sA[128 * LDA];
    int t = threadIdx.x;
    int R0 = blockIdx.x * 128;
    int row = t >> 1, colb = (t & 1) * 64;
    bool valid = (R0 + row) < N_NODES;
    const float* Xr = X + (size_t)(R0 + row) * 128 + colb;
    unsigned short* dp = sA + row * LDA + colb;
#pragma unroll
    for (int j = 0; j < 16; j++) {
        float4 v = valid ? *(const float4*)(Xr + j * 4) : make_float4(0.f, 0.f, 0.f, 0.f);
        ushort4 o;
        o.x = f2bf(v.x); o.y = f2bf(v.y); o.z = f2bf(v.z); o.w = f2bf(v.w);
        *(ushort4*)(dp + j * 4) = o;
    }
    __syncthreads();

    int wv = t >> 6, l = t & 63;
    int quad = l >> 4, lm = l & 15;

    bf16x8 a[2][4];
#pragma unroll
    for (int mt = 0; mt < 2; mt++)
#pragma unroll
        for (int ks = 0; ks < 4; ks++)
            a[mt][ks] = *(const bf16x8*)(sA + (wv * 32 + mt * 16 + lm) * LDA +
                                         ks * 32 + quad * 8);

    f32x4 acc[2][8] = {};
#pragma unroll
    for (int nt = 0; nt < 8; nt++) {
        bf16x8 b[4];
        const unsigned short* Wp = Wt + (nt * 16 + lm) * 128 + quad * 8;
#pragma unroll
        for (int ks = 0; ks < 4; ks++)
            b[ks] = *(const bf16x8*)(Wp + ks * 32);
#pragma unroll
        for (int mt = 0; mt < 2; mt++) {
            f32x4 c = acc[mt][nt];
#pragma unroll
            for (int ks = 0; ks < 4; ks++)
                c = __builtin_amdgcn_mfma_f32_16x16x32_bf16(a[mt][ks], b[ks], c, 0, 0, 0);
            acc[mt][nt] = c;
        }
    }

    int rbase = R0 + wv * 32 + quad * 4;
    float dv[2][4];
#pragma unroll
    for (int mt = 0; mt < 2; mt++)
#pragma unroll
        for (int reg = 0; reg < 4; reg++) {
            int r = rbase + mt * 16 + reg;
            dv[mt][reg] = (r < N_NODES) ? dinv[r] : 0.f;
        }
#pragma unroll
    for (int mt = 0; mt < 2; mt++)
#pragma unroll
        for (int nt = 0; nt < 8; nt++)
#pragma unroll
            for (int reg = 0; reg < 4; reg++) {
                int r = rbase + mt * 16 + reg;
                if (r < N_NODES)
                    Y[(size_t)r * 128 + nt * 16 + lm] = f2bf(acc[mt][nt][reg] * dv[mt][reg]);
            }
}

// -------- agg1: hb' = dinv * relu(dinv * (self + sum h0') + b1) -------------
// 16 nodes/block, 4 waves, 4 serial nodes per wave; batch-32 gather.
// Inputs pre-scaled (h0' = d*h0): per-edge weight is 1, no dinv gather.

__global__ __launch_bounds__(256) void k_agg1(const unsigned short* __restrict__ h0,
                                              const int* __restrict__ rowptr,
                                              const int* __restrict__ csr_src,
                                              const float* __restrict__ dinv,
                                              const float* __restrict__ b1,
                                              unsigned short* __restrict__ hb) {
    int t = threadIdx.x;
    int wv = t >> 6, lane = t & 63;
    int nodeBase = blockIdx.x * 16;
    int c2 = lane * 2;

#pragma unroll 1
    for (int j4 = 0; j4 < 4; j4++) {
        int i = __builtin_amdgcn_readfirstlane(nodeBase + wv * 4 + j4);
        float di = dinv[i];
        unsigned int sv = *(const unsigned int*)(h0 + (size_t)i * 128 + c2);
        float ax = bfl(sv), ay = bfh(sv);        // self term, weight 1
        int beg = rowptr[i], end = rowptr[i + 1];
        for (int p = beg; p < end; p += 32) {
            int s[32]; unsigned int r[32];
#pragma unroll
            for (int j = 0; j < 32; j++) {
                int q = p + j;
                s[j] = __builtin_nontemporal_load(csr_src + (q < end ? q : end - 1));
            }
#pragma unroll
            for (int j = 0; j < 32; j++)
                r[j] = *(const unsigned int*)(h0 + (size_t)s[j] * 128 + c2);
#pragma unroll
            for (int j = 0; j < 32; j++) {
                unsigned int v = (p + j < end) ? r[j] : 0u;
                ax += bfl(v);
                ay += bfh(v);
            }
        }
        ax = ax * di + b1[c2];
        ay = ay * di + b1[c2 + 1];
        ax = ax > 0.f ? ax : 0.f;
        ay = ay > 0.f ? ay : 0.f;
        ax *= di;                                // pre-scale for layer-2 gather
        ay *= di;
        unsigned int pk = ((unsigned int)f2bf(ay) << 16) | (unsigned int)f2bf(ax);
        *(unsigned int*)(hb + (size_t)i * 128 + c2) = pk;
    }
}

// ------- fused layer 2: g = dinv*(self + sum hb'); out = g @ WtC + bias -----
// Block = 256 thr / 4 waves / 16 nodes. Same batch-32 pre-scaled gather loop.

#define LDG 136

__global__ __launch_bounds__(256) void k_agg2g(const unsigned short* __restrict__ hb,
                                               const int* __restrict__ rowptr,
                                               const int* __restrict__ csr_src,
                                               const float* __restrict__ dinv,
                                               const unsigned short* __restrict__ WtC,
                                               const float* __restrict__ bmu,
                                               const float* __restrict__ bls,
                                               float* __restrict__ out) {
    __shared__ unsigned short g[16 * LDG];
    int t = threadIdx.x;
    int wv = t >> 6, lane = t & 63;
    int nodeBase = blockIdx.x * 16;
    int c2 = lane * 2;

#pragma unroll 1
    for (int j4 = 0; j4 < 4; j4++) {
        int i = __builtin_amdgcn_readfirstlane(nodeBase + wv * 4 + j4);
        float di = dinv[i];
        unsigned int sv = *(const unsigned int*)(hb + (size_t)i * 128 + c2);
        float ax = bfl(sv), ay = bfh(sv);
        int beg = rowptr[i], end = rowptr[i + 1];
        for (int p = beg; p < end; p += 32) {
            int s[32]; unsigned int r[32];
#pragma unroll
            for (int j = 0; j < 32; j++) {
                int q = p + j;
                s[j] = __builtin_nontemporal_load(csr_src + (q < end ? q : end - 1));
            }
#pragma unroll
            for (int j = 0; j < 32; j++)
                r[j] = *(const unsigned int*)(hb + (size_t)s[j] * 128 + c2);
#pragma unroll
            for (int j = 0; j < 32; j++) {
                unsigned int v = (p + j < end) ? r[j] : 0u;
                ax += bfl(v);
                ay += bfh(v);
            }
        }
        ax *= di;
        ay *= di;
        unsigned int pk = ((unsigned int)f2bf(ay) << 16) | (unsigned int)f2bf(ax);
        *(unsigned int*)(g + (wv * 4 + j4) * LDG + c2) = pk;
    }
    __syncthreads();

    // MFMA: wave wv computes output cols [wv*32, wv*32+32)
    int quad = lane >> 4, lm = lane & 15;
    bf16x8 a[4];
#pragma unroll
    for (int ks = 0; ks < 4; ks++)
        a[ks] = *(const bf16x8*)(g + lm * LDG + ks * 32 + quad * 8);

#pragma unroll
    for (int nt2 = 0; nt2 < 2; nt2++) {
        int nt = wv * 2 + nt2;
        f32x4 acc = {};
        const unsigned short* Wp = WtC + (nt * 16 + lm) * 128 + quad * 8;
#pragma unroll
        for (int ks = 0; ks < 4; ks++) {
            bf16x8 b = *(const bf16x8*)(Wp + ks * 32);
            acc = __builtin_amdgcn_mfma_f32_16x16x32_bf16(a[ks], b, acc, 0, 0, 0);
        }
        int col = nt * 16 + lm;
#pragma unroll
        for (int reg = 0; reg < 4; reg++) {
            int row = nodeBase + quad * 4 + reg;
            float v = acc[reg];
            if (col < 64)
                out[(size_t)row * 64 + col] = v + bmu[col];
            else
                out[(size_t)N_NODES * 64 + (size_t)row * 64 + (col - 64)] = v + bls[col - 64];
        }
    }
}

// ---------------- launch ----------------

extern "C" void kernel_launch(void* const* d_in, const int* in_sizes, int n_in,
                              void* d_out, int out_size, void* d_ws, size_t ws_size,
                              hipStream_t stream) {
    const float* x    = (const float*)d_in[0];
    const int*   ei   = (const int*)d_in[1];
    const float* W1   = (const float*)d_in[2];
    const float* b1   = (const float*)d_in[3];
    const float* Wmu  = (const float*)d_in[4];
    const float* bmu  = (const float*)d_in[5];
    const float* Wls  = (const float*)d_in[6];
    const float* bls  = (const float*)d_in[7];
    const int* src = ei;
    const int* dst = ei + N_EDGES;

    char* p = (char*)d_ws;
    unsigned short* bufA = (unsigned short*)p; p += (size_t)N_NODES * 128 * 2; // h0' (bf16, pre-scaled)
    unsigned short* bufH = (unsigned short*)p; p += (size_t)N_NODES * 128 * 2; // hb' (bf16, pre-scaled)
    unsigned short* Wt1  = (unsigned short*)p; p += 128 * 128 * 2;
    unsigned short* WtC  = (unsigned short*)p; p += 128 * 128 * 2;
    int*   bucketCnt = (int*)p; p += 256 * 4;
    int*   rowptr  = (int*)p;   p += 400016;
    float* dinv    = (float*)p; p += 400000;
    unsigned int* bucketed = (unsigned int*)p; p += (size_t)NB * CAP * 4;
    int*   csr_src = (int*)p;   p += (size_t)N_EDGES * 4;

    // CSR build (2 kernels + memset)
    hipMemsetAsync(bucketCnt, 0, NB * sizeof(int), stream);
    k_scatter1<<<NBLK, 256, 0, stream>>>(src, dst, bucketCnt, bucketed);
    k_phaseC<<<NB, 512, 0, stream>>>(bucketed, bucketCnt, rowptr, dinv, csr_src);

    k_prepW<<<64, 256, 0, stream>>>(W1, Wmu, Wls, Wt1, WtC);

    int gblk = (N_NODES + 127) / 128;   // 782

    // layer 1: h0' = dinv * (x @ W1) (MFMA) ; hb' = dinv*relu(dinv*agg + b1)
    k_gemm1<<<gblk, 256, 0, stream>>>(x, Wt1, dinv, bufA);
    k_agg1<<<N_NODES / 16, 256, 0, stream>>>(bufA, rowptr, csr_src, dinv, b1, bufH);

    // layer 2 (reordered): out = (dinv*(self+sum hb')) @ [Wmu|Wls] + bias, fused
    k_agg2g<<<N_NODES / 16, 256, 0, stream>>>(bufH, rowptr, csr_src, dinv,
                                              WtC, bmu, bls, (float*)d_out);
}

// Round 9
// 334.512 us; speedup vs baseline: 6.5686x; 1.0401x over previous
//
#include <hip/hip_runtime.h>
#include <hip/hip_bf16.h>
#include <stdint.h>

#define N_NODES 100000
#define IN_CH   128
#define HID     128
#define OUT_CH  64
#define N_EDGES 1600000

#define NB    196      // buckets of 512 nodes
#define NBLK  250      // edge-partition blocks for scatter
#define EPB   6400     // edges per block
#define CAP   10240    // padded bucket capacity (mean 8192, sigma~90)

typedef __attribute__((ext_vector_type(8))) short  bf16x8;
typedef __attribute__((ext_vector_type(4))) float  f32x4;

// ---------------- helpers ----------------

__device__ __forceinline__ unsigned short f2bf(float f) {   // RNE f32->bf16
    unsigned int u = __float_as_uint(f);
    u = (u + 0x7fffu + ((u >> 16) & 1u)) >> 16;
    return (unsigned short)u;
}
__device__ __forceinline__ float bfl(unsigned int u) { return __uint_as_float(u << 16); }
__device__ __forceinline__ float bfh(unsigned int u) { return __uint_as_float(u & 0xffff0000u); }

// ------------- CSR build, single-pass scatter (fused A+scan+B) --------------
// Per-block LDS histogram of its 6400 edges; block reserves per-bucket space
// via one global atomicAdd per bucket; scatters into capacity-padded buckets.
// Within-bucket order is non-deterministic (harmless: fp32 accum, reorder
// noise ~1e-7 << bf16 quantization).

__global__ __launch_bounds__(256) void k_scatter1(const int* __restrict__ src,
                                                  const int* __restrict__ dst,
                                                  int* __restrict__ bucketCnt,
                                                  unsigned int* __restrict__ bucketed) {
    __shared__ int hist[NB];
    int blk = blockIdx.x, t = threadIdx.x;
    if (t < NB) hist[t] = 0;
    __syncthreads();
    int base = blk * EPB;
#pragma unroll 5
    for (int k = 0; k < EPB / 256; k++) {
        int d = dst[base + k * 256 + t];
        atomicAdd(&hist[d >> 9], 1);
    }
    __syncthreads();
    if (t < NB) hist[t] = atomicAdd(&bucketCnt[t], hist[t]);   // reserve
    __syncthreads();
#pragma unroll 5
    for (int k = 0; k < EPB / 256; k++) {
        int e = base + k * 256 + t;
        int d = dst[e];
        int sv = src[e];
        int pos = atomicAdd(&hist[d >> 9], 1);
        bucketed[(size_t)(d >> 9) * CAP + pos] =
            ((unsigned int)sv << 9) | (unsigned int)(d & 511);
    }
}

// ------------- phaseC': per-bucket node sort -> CSR + dinv ------------------
// Each block scans the 196-entry bucketCnt in-LDS to get its global CSR base,
// then counts/sorts nodes within its bucket. ALSO folds the W-prep (bf16
// transpose + mu|ls concat) into the scan-barrier shadow: 196x512 threads
// cover the 2x16384 W elements with gid < 16384.

__global__ __launch_bounds__(512) void k_phaseC(const unsigned int* __restrict__ bucketed,
                                                const int* __restrict__ bucketCnt,
                                                int* __restrict__ rowptr,
                                                float* __restrict__ dinvg,
                                                int* __restrict__ csr_src,
                                                const float* __restrict__ W1,
                                                const float* __restrict__ Wmu,
                                                const float* __restrict__ Wls,
                                                unsigned short* __restrict__ Wt1,
                                                unsigned short* __restrict__ WtC) {
    __shared__ int cnt[512];
    __shared__ int cur[512];
    __shared__ int sdata[512];
    __shared__ int s_base, s_cnt;
    int b = blockIdx.x, t = threadIdx.x;

    // folded W-prep (independent work, fills barrier idle)
    int gid = b * 512 + t;
    if (gid < 16384) {
        int n = gid >> 7, k = gid & 127;
        Wt1[gid] = f2bf(W1[k * 128 + n]);
        WtC[gid] = f2bf((n < 64) ? Wmu[k * 64 + n] : Wls[k * 64 + (n - 64)]);
    }

    // in-block exclusive scan of bucket counts -> global base of bucket b
    int bv = (t < NB) ? bucketCnt[t] : 0;
    sdata[t] = bv;
    __syncthreads();
    int bval = bv;
    for (int off = 1; off < 512; off <<= 1) {
        int tmp = (t >= off) ? sdata[t - off] : 0;
        __syncthreads();
        bval += tmp;
        sdata[t] = bval;
        __syncthreads();
    }
    if (t == b) { s_base = bval - bv; s_cnt = bv; }
    __syncthreads();
    int base = s_base;
    int nEdge = s_cnt;

    const unsigned int* bk = bucketed + (size_t)b * CAP;
    int nodeBase = b << 9;
    int nNodes = N_NODES - nodeBase;
    if (nNodes > 512) nNodes = 512;

    cnt[t] = 0;
    __syncthreads();
    for (int e = t; e < nEdge; e += 512)
        atomicAdd(&cnt[bk[e] & 511], 1);
    __syncthreads();

    int s = cnt[t];
    sdata[t] = s;
    __syncthreads();
    int val = s;
    for (int off = 1; off < 512; off <<= 1) {
        int tmp = (t >= off) ? sdata[t - off] : 0;
        __syncthreads();
        val += tmp;
        sdata[t] = val;
        __syncthreads();
    }
    cur[t] = val - s;
    if (t < nNodes) {
        rowptr[nodeBase + t] = base + val - s;
        dinvg[nodeBase + t] = rsqrtf((float)s + 1.0f);
    }
    if (b == NB - 1 && t == 0) rowptr[N_NODES] = N_EDGES;
    __syncthreads();

    for (int e = t; e < nEdge; e += 512) {
        unsigned int u = bk[e];
        int pos = base + atomicAdd(&cur[u & 511], 1);
        csr_src[pos] = (int)(u >> 9);
    }
}

// ------ MFMA GEMM1: h0' = dinv * (x @ W1), node-major bf16 [node][128] ------
// v2: LDS-free. Each lane loads its A-fragment (8 consecutive floats of one
// X row) directly from global as 2x float4 and converts in-register — no
// staging pass, no barrier, no 34.8 KB LDS (occupancy no longer LDS-capped).

__global__ __launch_bounds__(256) void k_gemm1(const float* __restrict__ X,
                                               const unsigned short* __restrict__ Wt,
                                               const float* __restrict__ dinv,
                                               unsigned short* __restrict__ Y) {
    int t = threadIdx.x;
    int R0 = blockIdx.x * 128;
    int wv = t >> 6, l = t & 63;
    int quad = l >> 4, lm = l & 15;

    bf16x8 a[2][4];
#pragma unroll
    for (int mt = 0; mt < 2; mt++) {
        int r = R0 + wv * 32 + mt * 16 + lm;
        bool v = r < N_NODES;
        const float* Xp = X + (size_t)(v ? r : 0) * 128 + quad * 8;
#pragma unroll
        for (int ks = 0; ks < 4; ks++) {
            float4 x0 = v ? *(const float4*)(Xp + ks * 32)
                          : make_float4(0.f, 0.f, 0.f, 0.f);
            float4 x1 = v ? *(const float4*)(Xp + ks * 32 + 4)
                          : make_float4(0.f, 0.f, 0.f, 0.f);
            bf16x8 af;
            af[0] = (short)f2bf(x0.x); af[1] = (short)f2bf(x0.y);
            af[2] = (short)f2bf(x0.z); af[3] = (short)f2bf(x0.w);
            af[4] = (short)f2bf(x1.x); af[5] = (short)f2bf(x1.y);
            af[6] = (short)f2bf(x1.z); af[7] = (short)f2bf(x1.w);
            a[mt][ks] = af;
        }
    }

    f32x4 acc[2][8] = {};
#pragma unroll
    for (int nt = 0; nt < 8; nt++) {
        bf16x8 b[4];
        const unsigned short* Wp = Wt + (nt * 16 + lm) * 128 + quad * 8;
#pragma unroll
        for (int ks = 0; ks < 4; ks++)
            b[ks] = *(const bf16x8*)(Wp + ks * 32);
#pragma unroll
        for (int mt = 0; mt < 2; mt++) {
            f32x4 c = acc[mt][nt];
#pragma unroll
            for (int ks = 0; ks < 4; ks++)
                c = __builtin_amdgcn_mfma_f32_16x16x32_bf16(a[mt][ks], b[ks], c, 0, 0, 0);
            acc[mt][nt] = c;
        }
    }

    int rbase = R0 + wv * 32 + quad * 4;
    float dv[2][4];
#pragma unroll
    for (int mt = 0; mt < 2; mt++)
#pragma unroll
        for (int reg = 0; reg < 4; reg++) {
            int r = rbase + mt * 16 + reg;
            dv[mt][reg] = (r < N_NODES) ? dinv[r] : 0.f;
        }
#pragma unroll
    for (int mt = 0; mt < 2; mt++)
#pragma unroll
        for (int nt = 0; nt < 8; nt++)
#pragma unroll
            for (int reg = 0; reg < 4; reg++) {
                int r = rbase + mt * 16 + reg;
                if (r < N_NODES)
                    Y[(size_t)r * 128 + nt * 16 + lm] = f2bf(acc[mt][nt][reg] * dv[mt][reg]);
            }
}

// -------- agg1: hb' = dinv * relu(dinv * (self + sum h0') + b1) -------------
// 16 nodes/block, 4 waves, 4 serial nodes per wave; batch-32 gather.
// At the L2 fill-port roofline (194 MB/agg / 8 XCD / 91.5us = 265 GB/s/XCD
// ~= 128 B/cy): do not touch. Inputs pre-scaled (h0' = d*h0).

__global__ __launch_bounds__(256) void k_agg1(const unsigned short* __restrict__ h0,
                                              const int* __restrict__ rowptr,
                                              const int* __restrict__ csr_src,
                                              const float* __restrict__ dinv,
                                              const float* __restrict__ b1,
                                              unsigned short* __restrict__ hb) {
    int t = threadIdx.x;
    int wv = t >> 6, lane = t & 63;
    int nodeBase = blockIdx.x * 16;
    int c2 = lane * 2;

#pragma unroll 1
    for (int j4 = 0; j4 < 4; j4++) {
        int i = __builtin_amdgcn_readfirstlane(nodeBase + wv * 4 + j4);
        float di = dinv[i];
        unsigned int sv = *(const unsigned int*)(h0 + (size_t)i * 128 + c2);
        float ax = bfl(sv), ay = bfh(sv);        // self term, weight 1
        int beg = rowptr[i], end = rowptr[i + 1];
        for (int p = beg; p < end; p += 32) {
            int s[32]; unsigned int r[32];
#pragma unroll
            for (int j = 0; j < 32; j++) {
                int q = p + j;
                s[j] = __builtin_nontemporal_load(csr_src + (q < end ? q : end - 1));
            }
#pragma unroll
            for (int j = 0; j < 32; j++)
                r[j] = *(const unsigned int*)(h0 + (size_t)s[j] * 128 + c2);
#pragma unroll
            for (int j = 0; j < 32; j++) {
                unsigned int v = (p + j < end) ? r[j] : 0u;
                ax += bfl(v);
                ay += bfh(v);
            }
        }
        ax = ax * di + b1[c2];
        ay = ay * di + b1[c2 + 1];
        ax = ax > 0.f ? ax : 0.f;
        ay = ay > 0.f ? ay : 0.f;
        ax *= di;                                // pre-scale for layer-2 gather
        ay *= di;
        unsigned int pk = ((unsigned int)f2bf(ay) << 16) | (unsigned int)f2bf(ax);
        *(unsigned int*)(hb + (size_t)i * 128 + c2) = pk;
    }
}

// ------- fused layer 2: g = dinv*(self + sum hb'); out = g @ WtC + bias -----
// Block = 256 thr / 4 waves / 16 nodes. Same batch-32 pre-scaled gather loop.

#define LDG 136

__global__ __launch_bounds__(256) void k_agg2g(const unsigned short* __restrict__ hb,
                                               const int* __restrict__ rowptr,
                                               const int* __restrict__ csr_src,
                                               const float* __restrict__ dinv,
                                               const unsigned short* __restrict__ WtC,
                                               const float* __restrict__ bmu,
                                               const float* __restrict__ bls,
                                               float* __restrict__ out) {
    __shared__ unsigned short g[16 * LDG];
    int t = threadIdx.x;
    int wv = t >> 6, lane = t & 63;
    int nodeBase = blockIdx.x * 16;
    int c2 = lane * 2;

#pragma unroll 1
    for (int j4 = 0; j4 < 4; j4++) {
        int i = __builtin_amdgcn_readfirstlane(nodeBase + wv * 4 + j4);
        float di = dinv[i];
        unsigned int sv = *(const unsigned int*)(hb + (size_t)i * 128 + c2);
        float ax = bfl(sv), ay = bfh(sv);
        int beg = rowptr[i], end = rowptr[i + 1];
        for (int p = beg; p < end; p += 32) {
            int s[32]; unsigned int r[32];
#pragma unroll
            for (int j = 0; j < 32; j++) {
                int q = p + j;
                s[j] = __builtin_nontemporal_load(csr_src + (q < end ? q : end - 1));
            }
#pragma unroll
            for (int j = 0; j < 32; j++)
                r[j] = *(const unsigned int*)(hb + (size_t)s[j] * 128 + c2);
#pragma unroll
            for (int j = 0; j < 32; j++) {
                unsigned int v = (p + j < end) ? r[j] : 0u;
                ax += bfl(v);
                ay += bfh(v);
            }
        }
        ax *= di;
        ay *= di;
        unsigned int pk = ((unsigned int)f2bf(ay) << 16) | (unsigned int)f2bf(ax);
        *(unsigned int*)(g + (wv * 4 + j4) * LDG + c2) = pk;
    }
    __syncthreads();

    // MFMA: wave wv computes output cols [wv*32, wv*32+32)
    int quad = lane >> 4, lm = lane & 15;
    bf16x8 a[4];
#pragma unroll
    for (int ks = 0; ks < 4; ks++)
        a[ks] = *(const bf16x8*)(g + lm * LDG + ks * 32 + quad * 8);

#pragma unroll
    for (int nt2 = 0; nt2 < 2; nt2++) {
        int nt = wv * 2 + nt2;
        f32x4 acc = {};
        const unsigned short* Wp = WtC + (nt * 16 + lm) * 128 + quad * 8;
#pragma unroll
        for (int ks = 0; ks < 4; ks++) {
            bf16x8 b = *(const bf16x8*)(Wp + ks * 32);
            acc = __builtin_amdgcn_mfma_f32_16x16x32_bf16(a[ks], b, acc, 0, 0, 0);
        }
        int col = nt * 16 + lm;
#pragma unroll
        for (int reg = 0; reg < 4; reg++) {
            int row = nodeBase + quad * 4 + reg;
            float v = acc[reg];
            if (col < 64)
                out[(size_t)row * 64 + col] = v + bmu[col];
            else
                out[(size_t)N_NODES * 64 + (size_t)row * 64 + (col - 64)] = v + bls[col - 64];
        }
    }
}

// ---------------- launch ----------------

extern "C" void kernel_launch(void* const* d_in, const int* in_sizes, int n_in,
                              void* d_out, int out_size, void* d_ws, size_t ws_size,
                              hipStream_t stream) {
    const float* x    = (const float*)d_in[0];
    const int*   ei   = (const int*)d_in[1];
    const float* W1   = (const float*)d_in[2];
    const float* b1   = (const float*)d_in[3];
    const float* Wmu  = (const float*)d_in[4];
    const float* bmu  = (const float*)d_in[5];
    const float* Wls  = (const float*)d_in[6];
    const float* bls  = (const float*)d_in[7];
    const int* src = ei;
    const int* dst = ei + N_EDGES;

    char* p = (char*)d_ws;
    unsigned short* bufA = (unsigned short*)p; p += (size_t)N_NODES * 128 * 2; // h0' (bf16, pre-scaled)
    unsigned short* bufH = (unsigned short*)p; p += (size_t)N_NODES * 128 * 2; // hb' (bf16, pre-scaled)
    unsigned short* Wt1  = (unsigned short*)p; p += 128 * 128 * 2;
    unsigned short* WtC  = (unsigned short*)p; p += 128 * 128 * 2;
    int*   bucketCnt = (int*)p; p += 256 * 4;
    int*   rowptr  = (int*)p;   p += 400016;
    float* dinv    = (float*)p; p += 400000;
    unsigned int* bucketed = (unsigned int*)p; p += (size_t)NB * CAP * 4;
    int*   csr_src = (int*)p;   p += (size_t)N_EDGES * 4;

    // CSR build + W prep (2 kernels + memset)
    hipMemsetAsync(bucketCnt, 0, NB * sizeof(int), stream);
    k_scatter1<<<NBLK, 256, 0, stream>>>(src, dst, bucketCnt, bucketed);
    k_phaseC<<<NB, 512, 0, stream>>>(bucketed, bucketCnt, rowptr, dinv, csr_src,
                                     W1, Wmu, Wls, Wt1, WtC);

    int gblk = (N_NODES + 127) / 128;   // 782

    // layer 1: h0' = dinv * (x @ W1) (MFMA, LDS-free) ; hb' = dinv*relu(dinv*agg + b1)
    k_gemm1<<<gblk, 256, 0, stream>>>(x, Wt1, dinv, bufA);
    k_agg1<<<N_NODES / 16, 256, 0, stream>>>(bufA, rowptr, csr_src, dinv, b1, bufH);

    // layer 2 (reordered): out = (dinv*(self+sum hb')) @ [Wmu|Wls] + bias, fused
    k_agg2g<<<N_NODES / 16, 256, 0, stream>>>(bufH, rowptr, csr_src, dinv,
                                              WtC, bmu, bls, (float*)d_out);
}

// Round 10
// 333.020 us; speedup vs baseline: 6.5980x; 1.0045x over previous
//
#include <hip/hip_runtime.h>
#include <hip/hip_bf16.h>
#include <stdint.h>

#define N_NODES 100000
#define IN_CH   128
#define HID     128
#define OUT_CH  64
#define N_EDGES 1600000

#define NB    196      // buckets of 512 nodes
#define NBLK  250      // edge-partition blocks for scatter
#define EPB   6400     // edges per block
#define CAP   10240    // padded bucket capacity (mean 8192, sigma~90)

typedef __attribute__((ext_vector_type(8))) short  bf16x8;
typedef __attribute__((ext_vector_type(4))) float  f32x4;

// ---------------- helpers ----------------

__device__ __forceinline__ unsigned short f2bf(float f) {   // RNE f32->bf16
    unsigned int u = __float_as_uint(f);
    u = (u + 0x7fffu + ((u >> 16) & 1u)) >> 16;
    return (unsigned short)u;
}
__device__ __forceinline__ float bfl(unsigned int u) { return __uint_as_float(u << 16); }
__device__ __forceinline__ float bfh(unsigned int u) { return __uint_as_float(u & 0xffff0000u); }

// ------------- CSR build, single-pass scatter (fused A+scan+B) --------------
// v2: pass 1 reads src+dst ONCE (coalesced), stashes packed edge + bucket id
// in LDS; pass 2 scatters from LDS (no global re-read). Block reserves
// per-bucket space via one global atomicAdd per bucket. Within-bucket order
// non-deterministic (harmless: fp32 accum, reorder noise ~1e-7 << bf16 quant).

__global__ __launch_bounds__(256) void k_scatter1(const int* __restrict__ src,
                                                  const int* __restrict__ dst,
                                                  int* __restrict__ bucketCnt,
                                                  unsigned int* __restrict__ bucketed) {
    __shared__ int hist[NB];
    __shared__ unsigned int pk[EPB];        // 25.6 KB
    __shared__ unsigned char bkt[EPB];      // 6.4 KB
    int blk = blockIdx.x, t = threadIdx.x;
    if (t < NB) hist[t] = 0;
    __syncthreads();
    int base = blk * EPB;
#pragma unroll 5
    for (int k = 0; k < EPB / 256; k++) {
        int idx = k * 256 + t;
        int e = base + idx;
        int d = dst[e];
        int sv = src[e];
        int b = d >> 9;
        atomicAdd(&hist[b], 1);
        pk[idx] = ((unsigned int)sv << 9) | (unsigned int)(d & 511);
        bkt[idx] = (unsigned char)b;
    }
    __syncthreads();
    if (t < NB) hist[t] = atomicAdd(&bucketCnt[t], hist[t]);   // reserve
    __syncthreads();
#pragma unroll 5
    for (int k = 0; k < EPB / 256; k++) {
        int idx = k * 256 + t;
        int b = bkt[idx];
        int pos = atomicAdd(&hist[b], 1);
        bucketed[(size_t)b * CAP + pos] = pk[idx];
    }
}

// ------------- phaseC': per-bucket node sort -> CSR + dinv ------------------
// v2: shuffle-based scans. Global base = block REDUCTION of bucketCnt[j<b]
// (wave xor-reduce + 8-way combine); node scan = wave shfl_up scan + cross-
// wave combine (2 barriers vs 18). Also folds W-prep (bf16 transpose +
// mu|ls concat) into the idle shadow: 196x512 threads cover 16384 W elems.

__global__ __launch_bounds__(512) void k_phaseC(const unsigned int* __restrict__ bucketed,
                                                const int* __restrict__ bucketCnt,
                                                int* __restrict__ rowptr,
                                                float* __restrict__ dinvg,
                                                int* __restrict__ csr_src,
                                                const float* __restrict__ W1,
                                                const float* __restrict__ Wmu,
                                                const float* __restrict__ Wls,
                                                unsigned short* __restrict__ Wt1,
                                                unsigned short* __restrict__ WtC) {
    __shared__ int cnt[512];
    __shared__ int cur[512];
    __shared__ int wtmp[8];
    __shared__ int s_base;
    int b = blockIdx.x, t = threadIdx.x;
    int l = t & 63, w = t >> 6;

    // folded W-prep (independent work)
    int gid = b * 512 + t;
    if (gid < 16384) {
        int n = gid >> 7, k = gid & 127;
        Wt1[gid] = f2bf(W1[k * 128 + n]);
        WtC[gid] = f2bf((n < 64) ? Wmu[k * 64 + n] : Wls[k * 64 + (n - 64)]);
    }

    // base = sum_{j<b} bucketCnt[j]  (block reduction, no scan needed)
    int bv = (t < b) ? bucketCnt[t] : 0;
#pragma unroll
    for (int off = 32; off; off >>= 1) bv += __shfl_xor(bv, off);
    if (l == 0) wtmp[w] = bv;
    __syncthreads();
    if (t == 0) {
        int sum = 0;
#pragma unroll
        for (int i = 0; i < 8; i++) sum += wtmp[i];
        s_base = sum;
    }
    cnt[t] = 0;
    __syncthreads();
    int base = s_base;
    int nEdge = bucketCnt[b];

    const unsigned int* bk = bucketed + (size_t)b * CAP;
    int nodeBase = b << 9;
    int nNodes = N_NODES - nodeBase;
    if (nNodes > 512) nNodes = 512;

    for (int e = t; e < nEdge; e += 512)
        atomicAdd(&cnt[bk[e] & 511], 1);
    __syncthreads();

    // inclusive block scan of cnt via wave shfl_up + cross-wave combine
    int s = cnt[t];
    int sc = s;
#pragma unroll
    for (int off = 1; off < 64; off <<= 1) {
        int u = __shfl_up(sc, off);
        if (l >= off) sc += u;
    }
    if (l == 63) wtmp[w] = sc;
    __syncthreads();
    if (w == 0) {
        int x = (l < 8) ? wtmp[l] : 0;
#pragma unroll
        for (int off = 1; off < 8; off <<= 1) {
            int u = __shfl_up(x, off);
            if (l >= off) x += u;
        }
        if (l < 8) wtmp[l] = x;
    }
    __syncthreads();
    int excl = sc + (w ? wtmp[w - 1] : 0) - s;

    cur[t] = excl;
    if (t < nNodes) {
        rowptr[nodeBase + t] = base + excl;
        dinvg[nodeBase + t] = rsqrtf((float)s + 1.0f);
    }
    if (b == NB - 1 && t == 0) rowptr[N_NODES] = N_EDGES;
    __syncthreads();

    for (int e = t; e < nEdge; e += 512) {
        unsigned int u = bk[e];
        int pos = base + atomicAdd(&cur[u & 511], 1);
        csr_src[pos] = (int)(u >> 9);
    }
}

// ------ MFMA GEMM1: h0' = dinv * (x @ W1), node-major bf16 [node][128] ------
// LDS-free: each lane loads its A-fragment (8 consecutive floats of one X
// row) directly from global as 2x float4 and converts in-register.

__global__ __launch_bounds__(256) void k_gemm1(const float* __restrict__ X,
                                               const unsigned short* __restrict__ Wt,
                                               const float* __restrict__ dinv,
                                               unsigned short* __restrict__ Y) {
    int t = threadIdx.x;
    int R0 = blockIdx.x * 128;
    int wv = t >> 6, l = t & 63;
    int quad = l >> 4, lm = l & 15;

    bf16x8 a[2][4];
#pragma unroll
    for (int mt = 0; mt < 2; mt++) {
        int r = R0 + wv * 32 + mt * 16 + lm;
        bool v = r < N_NODES;
        const float* Xp = X + (size_t)(v ? r : 0) * 128 + quad * 8;
#pragma unroll
        for (int ks = 0; ks < 4; ks++) {
            float4 x0 = v ? *(const float4*)(Xp + ks * 32)
                          : make_float4(0.f, 0.f, 0.f, 0.f);
            float4 x1 = v ? *(const float4*)(Xp + ks * 32 + 4)
                          : make_float4(0.f, 0.f, 0.f, 0.f);
            bf16x8 af;
            af[0] = (short)f2bf(x0.x); af[1] = (short)f2bf(x0.y);
            af[2] = (short)f2bf(x0.z); af[3] = (short)f2bf(x0.w);
            af[4] = (short)f2bf(x1.x); af[5] = (short)f2bf(x1.y);
            af[6] = (short)f2bf(x1.z); af[7] = (short)f2bf(x1.w);
            a[mt][ks] = af;
        }
    }

    f32x4 acc[2][8] = {};
#pragma unroll
    for (int nt = 0; nt < 8; nt++) {
        bf16x8 b[4];
        const unsigned short* Wp = Wt + (nt * 16 + lm) * 128 + quad * 8;
#pragma unroll
        for (int ks = 0; ks < 4; ks++)
            b[ks] = *(const bf16x8*)(Wp + ks * 32);
#pragma unroll
        for (int mt = 0; mt < 2; mt++) {
            f32x4 c = acc[mt][nt];
#pragma unroll
            for (int ks = 0; ks < 4; ks++)
                c = __builtin_amdgcn_mfma_f32_16x16x32_bf16(a[mt][ks], b[ks], c, 0, 0, 0);
            acc[mt][nt] = c;
        }
    }

    int rbase = R0 + wv * 32 + quad * 4;
    float dv[2][4];
#pragma unroll
    for (int mt = 0; mt < 2; mt++)
#pragma unroll
        for (int reg = 0; reg < 4; reg++) {
            int r = rbase + mt * 16 + reg;
            dv[mt][reg] = (r < N_NODES) ? dinv[r] : 0.f;
        }
#pragma unroll
    for (int mt = 0; mt < 2; mt++)
#pragma unroll
        for (int nt = 0; nt < 8; nt++)
#pragma unroll
            for (int reg = 0; reg < 4; reg++) {
                int r = rbase + mt * 16 + reg;
                if (r < N_NODES)
                    Y[(size_t)r * 128 + nt * 16 + lm] = f2bf(acc[mt][nt][reg] * dv[mt][reg]);
            }
}

// -------- agg1: hb' = dinv * relu(dinv * (self + sum h0') + b1) -------------
// 16 nodes/block, 4 waves, 4 serial nodes per wave; batch-32 gather.
// At the per-XCD L2-fill floor (each XCD must see the whole 25.6 MB table +
// 6.4 MB csr; random graph => no locality): do not touch.

__global__ __launch_bounds__(256) void k_agg1(const unsigned short* __restrict__ h0,
                                              const int* __restrict__ rowptr,
                                              const int* __restrict__ csr_src,
                                              const float* __restrict__ dinv,
                                              const float* __restrict__ b1,
                                              unsigned short* __restrict__ hb) {
    int t = threadIdx.x;
    int wv = t >> 6, lane = t & 63;
    int nodeBase = blockIdx.x * 16;
    int c2 = lane * 2;

#pragma unroll 1
    for (int j4 = 0; j4 < 4; j4++) {
        int i = __builtin_amdgcn_readfirstlane(nodeBase + wv * 4 + j4);
        float di = dinv[i];
        unsigned int sv = *(const unsigned int*)(h0 + (size_t)i * 128 + c2);
        float ax = bfl(sv), ay = bfh(sv);        // self term, weight 1
        int beg = rowptr[i], end = rowptr[i + 1];
        for (int p = beg; p < end; p += 32) {
            int s[32]; unsigned int r[32];
#pragma unroll
            for (int j = 0; j < 32; j++) {
                int q = p + j;
                s[j] = __builtin_nontemporal_load(csr_src + (q < end ? q : end - 1));
            }
#pragma unroll
            for (int j = 0; j < 32; j++)
                r[j] = *(const unsigned int*)(h0 + (size_t)s[j] * 128 + c2);
#pragma unroll
            for (int j = 0; j < 32; j++) {
                unsigned int v = (p + j < end) ? r[j] : 0u;
                ax += bfl(v);
                ay += bfh(v);
            }
        }
        ax = ax * di + b1[c2];
        ay = ay * di + b1[c2 + 1];
        ax = ax > 0.f ? ax : 0.f;
        ay = ay > 0.f ? ay : 0.f;
        ax *= di;                                // pre-scale for layer-2 gather
        ay *= di;
        unsigned int pk2 = ((unsigned int)f2bf(ay) << 16) | (unsigned int)f2bf(ax);
        *(unsigned int*)(hb + (size_t)i * 128 + c2) = pk2;
    }
}

// ------- fused layer 2: g = dinv*(self + sum hb'); out = g @ WtC + bias -----
// Block = 256 thr / 4 waves / 16 nodes. Same batch-32 pre-scaled gather loop.

#define LDG 136

__global__ __launch_bounds__(256) void k_agg2g(const unsigned short* __restrict__ hb,
                                               const int* __restrict__ rowptr,
                                               const int* __restrict__ csr_src,
                                               const float* __restrict__ dinv,
                                               const unsigned short* __restrict__ WtC,
                                               const float* __restrict__ bmu,
                                               const float* __restrict__ bls,
                                               float* __restrict__ out) {
    __shared__ unsigned short g[16 * LDG];
    int t = threadIdx.x;
    int wv = t >> 6, lane = t & 63;
    int nodeBase = blockIdx.x * 16;
    int c2 = lane * 2;

#pragma unroll 1
    for (int j4 = 0; j4 < 4; j4++) {
        int i = __builtin_amdgcn_readfirstlane(nodeBase + wv * 4 + j4);
        float di = dinv[i];
        unsigned int sv = *(const unsigned int*)(hb + (size_t)i * 128 + c2);
        float ax = bfl(sv), ay = bfh(sv);
        int beg = rowptr[i], end = rowptr[i + 1];
        for (int p = beg; p < end; p += 32) {
            int s[32]; unsigned int r[32];
#pragma unroll
            for (int j = 0; j < 32; j++) {
                int q = p + j;
                s[j] = __builtin_nontemporal_load(csr_src + (q < end ? q : end - 1));
            }
#pragma unroll
            for (int j = 0; j < 32; j++)
                r[j] = *(const unsigned int*)(hb + (size_t)s[j] * 128 + c2);
#pragma unroll
            for (int j = 0; j < 32; j++) {
                unsigned int v = (p + j < end) ? r[j] : 0u;
                ax += bfl(v);
                ay += bfh(v);
            }
        }
        ax *= di;
        ay *= di;
        unsigned int pk2 = ((unsigned int)f2bf(ay) << 16) | (unsigned int)f2bf(ax);
        *(unsigned int*)(g + (wv * 4 + j4) * LDG + c2) = pk2;
    }
    __syncthreads();

    // MFMA: wave wv computes output cols [wv*32, wv*32+32)
    int quad = lane >> 4, lm = lane & 15;
    bf16x8 a[4];
#pragma unroll
    for (int ks = 0; ks < 4; ks++)
        a[ks] = *(const bf16x8*)(g + lm * LDG + ks * 32 + quad * 8);

#pragma unroll
    for (int nt2 = 0; nt2 < 2; nt2++) {
        int nt = wv * 2 + nt2;
        f32x4 acc = {};
        const unsigned short* Wp = WtC + (nt * 16 + lm) * 128 + quad * 8;
#pragma unroll
        for (int ks = 0; ks < 4; ks++) {
            bf16x8 b = *(const bf16x8*)(Wp + ks * 32);
            acc = __builtin_amdgcn_mfma_f32_16x16x32_bf16(a[ks], b, acc, 0, 0, 0);
        }
        int col = nt * 16 + lm;
#pragma unroll
        for (int reg = 0; reg < 4; reg++) {
            int row = nodeBase + quad * 4 + reg;
            float v = acc[reg];
            if (col < 64)
                out[(size_t)row * 64 + col] = v + bmu[col];
            else
                out[(size_t)N_NODES * 64 + (size_t)row * 64 + (col - 64)] = v + bls[col - 64];
        }
    }
}

// ---------------- launch ----------------

extern "C" void kernel_launch(void* const* d_in, const int* in_sizes, int n_in,
                              void* d_out, int out_size, void* d_ws, size_t ws_size,
                              hipStream_t stream) {
    const float* x    = (const float*)d_in[0];
    const int*   ei   = (const int*)d_in[1];
    const float* W1   = (const float*)d_in[2];
    const float* b1   = (const float*)d_in[3];
    const float* Wmu  = (const float*)d_in[4];
    const float* bmu  = (const float*)d_in[5];
    const float* Wls  = (const float*)d_in[6];
    const float* bls  = (const float*)d_in[7];
    const int* src = ei;
    const int* dst = ei + N_EDGES;

    char* p = (char*)d_ws;
    unsigned short* bufA = (unsigned short*)p; p += (size_t)N_NODES * 128 * 2; // h0' (bf16, pre-scaled)
    unsigned short* bufH = (unsigned short*)p; p += (size_t)N_NODES * 128 * 2; // hb' (bf16, pre-scaled)
    unsigned short* Wt1  = (unsigned short*)p; p += 128 * 128 * 2;
    unsigned short* WtC  = (unsigned short*)p; p += 128 * 128 * 2;
    int*   bucketCnt = (int*)p; p += 256 * 4;
    int*   rowptr  = (int*)p;   p += 400016;
    float* dinv    = (float*)p; p += 400000;
    unsigned int* bucketed = (unsigned int*)p; p += (size_t)NB * CAP * 4;
    int*   csr_src = (int*)p;   p += (size_t)N_EDGES * 4;

    // CSR build + W prep (2 kernels + memset)
    hipMemsetAsync(bucketCnt, 0, NB * sizeof(int), stream);
    k_scatter1<<<NBLK, 256, 0, stream>>>(src, dst, bucketCnt, bucketed);
    k_phaseC<<<NB, 512, 0, stream>>>(bucketed, bucketCnt, rowptr, dinv, csr_src,
                                     W1, Wmu, Wls, Wt1, WtC);

    int gblk = (N_NODES + 127) / 128;   // 782

    // layer 1: h0' = dinv * (x @ W1) (MFMA, LDS-free) ; hb' = dinv*relu(dinv*agg + b1)
    k_gemm1<<<gblk, 256, 0, stream>>>(x, Wt1, dinv, bufA);
    k_agg1<<<N_NODES / 16, 256, 0, stream>>>(bufA, rowptr, csr_src, dinv, b1, bufH);

    // layer 2 (reordered): out = (dinv*(self+sum hb')) @ [Wmu|Wls] + bias, fused
    k_agg2g<<<N_NODES / 16, 256, 0, stream>>>(bufH, rowptr, csr_src, dinv,
                                              WtC, bmu, bls, (float*)d_out);
}